// Round 1
// baseline (257.949 us; speedup 1.0000x reference)
//
#include <hip/hip_runtime.h>
#include <hip/hip_bf16.h>
#include <stdint.h>

#define NCOLS 8192
#define BS    256
#define NB    16
#define NT    64

typedef float    f32x4  __attribute__((ext_vector_type(4)));
typedef short    bf16x8 __attribute__((ext_vector_type(8)));
typedef unsigned u32x4  __attribute__((ext_vector_type(4)));

// RNE-pack two fp32 into one dword of two bf16 (lo = first arg)
__device__ __forceinline__ unsigned pack2(float lo, float hi) {
  unsigned a = __builtin_bit_cast(unsigned, lo);
  unsigned b = __builtin_bit_cast(unsigned, hi);
  a += 0x7FFFu + ((a >> 16) & 1u);
  b += 0x7FFFu + ((b >> 16) & 1u);
  return (a >> 16) | (b & 0xFFFF0000u);
}

// Convert W (16x256x256 fp32) -> bf16 in ws. 8 elems/thread.
__global__ __launch_bounds__(256) void wcvt_kernel(const float* __restrict__ Wf,
                                                   unsigned* __restrict__ Wb) {
  int i = blockIdx.x * 256 + threadIdx.x;
  f32x4 a = ((const f32x4*)Wf)[2 * i];
  f32x4 c = ((const f32x4*)Wf)[2 * i + 1];
  u32x4 o;
  o.x = pack2(a.x, a.y); o.y = pack2(a.z, a.w);
  o.z = pack2(c.x, c.y); o.w = pack2(c.z, c.w);
  ((u32x4*)Wb)[i] = o;
}

// One wg: block b (M=256 rows of W), NT=64 output cols. 4 waves split M.
// X tile staged transposed+swizzled in LDS as bf16; W read as bf16 A-frags from L2.
template<bool USE_WS>
__global__ __launch_bounds__(256)
void bg_kernel(const float* __restrict__ X, const float* __restrict__ Wf,
               const unsigned short* __restrict__ Wb, float* __restrict__ out) {
  __shared__ unsigned xs[NT * 128];  // [n][kd] dwords, XOR-swizzled, 32 KiB
  const int b    = blockIdx.y;
  const int n0   = blockIdx.x * NT;
  const int t    = threadIdx.x;
  const int wid  = t >> 6;
  const int lane = t & 63;

  // ---- stage X tile: K=256 rows x NT=64 cols, fp32 -> bf16, transpose to [n][k]
  {
    const int sub = lane & 3;        // k-pair within 8-row slab
    const int cg  = lane >> 2;       // col group: n = 4*cg..4*cg+3
    const float* xb = X + (size_t)b * BS * NCOLS + n0 + 4 * cg;
    const int krow = wid * 8 + sub * 2;
#pragma unroll
    for (int p = 0; p < 8; ++p) {
      const int k0 = p * 32 + krow;
      f32x4 r0 = *(const f32x4*)(xb + (size_t)k0 * NCOLS);
      f32x4 r1 = *(const f32x4*)(xb + (size_t)(k0 + 1) * NCOLS);
      const int kd = k0 >> 1;
#pragma unroll
      for (int j = 0; j < 4; ++j) {
        const int n = 4 * cg + j;
        const int f = (n ^ (n >> 2)) & 7;
        xs[n * 128 + (kd ^ (f << 2))] = pack2(r0[j], r1[j]);
      }
    }
  }
  __syncthreads();

  // ---- compute: wave wid handles rows [wid*64, wid*64+64) x all 64 cols
  const int ln16 = lane & 15;
  const int quad = lane >> 4;
  f32x4 acc[4][4] = {};

#pragma unroll
  for (int ks = 0; ks < 8; ++ks) {
    bf16x8 bfr[4];
#pragma unroll
    for (int nt = 0; nt < 4; ++nt) {
      const int n = nt * 16 + ln16;
      const int f = (n ^ (n >> 2)) & 7;
      const int ad = n * 128 + ((ks * 16 + quad * 4) ^ (f << 2));
      bfr[nt] = *(const bf16x8*)(&xs[ad]);
    }
    bf16x8 afr[4];
#pragma unroll
    for (int mt = 0; mt < 4; ++mt) {
      const int m = wid * 64 + mt * 16 + ln16;
      const size_t off = ((size_t)(b * BS + m)) * BS + ks * 32 + quad * 8;
      if (USE_WS) {
        afr[mt] = *(const bf16x8*)(Wb + off);
      } else {
        f32x4 w0 = *(const f32x4*)(Wf + off);
        f32x4 w1 = *(const f32x4*)(Wf + off + 4);
        union { unsigned u[4]; bf16x8 v; } cv;
        cv.u[0] = pack2(w0.x, w0.y); cv.u[1] = pack2(w0.z, w0.w);
        cv.u[2] = pack2(w1.x, w1.y); cv.u[3] = pack2(w1.z, w1.w);
        afr[mt] = cv.v;
      }
    }
#pragma unroll
    for (int mt = 0; mt < 4; ++mt)
#pragma unroll
      for (int nt = 0; nt < 4; ++nt)
        acc[mt][nt] = __builtin_amdgcn_mfma_f32_16x16x32_bf16(afr[mt], bfr[nt],
                                                              acc[mt][nt], 0, 0, 0);
  }

  // ---- epilogue: C/D layout col=lane&15, row=quad*4+r
#pragma unroll
  for (int mt = 0; mt < 4; ++mt) {
    const int m = wid * 64 + mt * 16 + quad * 4;
#pragma unroll
    for (int r = 0; r < 4; ++r) {
      float* orow = out + (size_t)(b * BS + m + r) * NCOLS + n0 + ln16;
#pragma unroll
      for (int nt = 0; nt < 4; ++nt) orow[nt * 16] = acc[mt][nt][r];
    }
  }
}

extern "C" void kernel_launch(void* const* d_in, const int* in_sizes, int n_in,
                              void* d_out, int out_size, void* d_ws, size_t ws_size,
                              hipStream_t stream) {
  const float* X  = (const float*)d_in[0];
  const float* Wf = (const float*)d_in[1];
  float* out      = (float*)d_out;
  dim3 grid(NCOLS / NT, NB);
  const size_t wneed = (size_t)NB * BS * BS * sizeof(unsigned short);
  if (ws_size >= wneed) {
    unsigned* Wb = (unsigned*)d_ws;
    wcvt_kernel<<<dim3((NB * BS * BS) / (256 * 8)), 256, 0, stream>>>(Wf, Wb);
    bg_kernel<true><<<grid, 256, 0, stream>>>(X, Wf, (const unsigned short*)Wb, out);
  } else {
    bg_kernel<false><<<grid, 256, 0, stream>>>(X, Wf, nullptr, out);
  }
}